// Round 3
// baseline (662.378 us; speedup 1.0000x reference)
//
#include <hip/hip_runtime.h>
#include <hip/hip_cooperative_groups.h>
#include <math.h>

namespace cg = cooperative_groups;

#define BB 16
#define SS 2048
#define DD 768
#define NROW (BB * SS) // 32768
#define NBLK 1024      // cooperative grid: 4 blocks/CU on 256 CUs
#define NSLICE 16      // o-dimension split for weight fold

// ws layout (float offsets)
#define PART_OFF  0                        // NSLICE*2304 floats: partial w3 sums
#define W3_OFF    (PART_OFF + NSLICE*2304) // 2304 floats: w3[k][i]
#define BIAS_OFF  (W3_OFF + 2304)          // 1 float
#define E0_OFF    (BIAS_OFF + 64)          // NROW floats each: e_k[t] = sum_i w3[k][i]*x[t][i]
#define E1_OFF    (E0_OFF + NROW)
#define E2_OFF    (E1_OFF + NROW)
#define WCUR_OFF  (E2_OFF + NROW)          // NROW floats
#define WNEXT_OFF (WCUR_OFF + NROW)        // NROW floats
#define FT_OFF    (WNEXT_OFF + NROW)       // NROW ints: fire time of output row j
#define LEN_OFF   (FT_OFF + NROW)          // BB ints

// Single cooperative kernel: fold -> dots -> scan -> emit with grid-wide syncs.
// __launch_bounds__(256,4): cap 128 VGPR -> 4 blocks/CU resident (needed for coop launch).
__global__ __launch_bounds__(256, 4) void cif_mega(
    const float* __restrict__ x, const int* __restrict__ lens,
    const float* __restrict__ conv_w, const float* __restrict__ conv_b,
    const float* __restrict__ lin_w, const float* __restrict__ lin_b,
    float* __restrict__ ws, float* __restrict__ out) {
  cg::grid_group grid = cg::this_grid();
  __shared__ float w3s[2304];
  __shared__ double sscan[256];

  const int tid = threadIdx.x;
  const int blk = blockIdx.x;
  const int wave = tid >> 6, lane = tid & 63;

  // ---- P0a: partial weight fold. blocks [0,144): (slice, cb). ----
  if (blk < NSLICE * 9) {
    int slice = blk / 9, cb = blk % 9;
    int c = cb * 256 + tid; // [0,2304)
    int o0 = slice * (DD / NSLICE);
    float acc = 0.f;
#pragma unroll 4
    for (int oo = 0; oo < DD / NSLICE; ++oo) {
      int o = o0 + oo;
      acc = fmaf(lin_w[o], conv_w[(size_t)o * 2304 + c], acc); // coalesced over c
    }
    ws[PART_OFF + slice * 2304 + c] = acc;
  }
  grid.sync();

  // ---- P0b: reduce partials -> w3; block 9 computes effective bias. ----
  if (blk < 9) {
    int c = blk * 256 + tid;
    float acc = 0.f;
#pragma unroll
    for (int s = 0; s < NSLICE; ++s) acc += ws[PART_OFF + s * 2304 + c];
    int i = c / 3, k = c % 3;
    ws[W3_OFF + k * DD + i] = acc;
  } else if (blk == 9) {
    __shared__ float red[256];
    float p = 0.f;
    for (int o = tid; o < DD; o += 256) p = fmaf(lin_w[o], conv_b[o], p);
    red[tid] = p;
    __syncthreads();
    for (int off = 128; off > 0; off >>= 1) {
      if (tid < off) red[tid] += red[tid + off];
      __syncthreads();
    }
    if (tid == 0) ws[BIAS_OFF] = red[0] + lin_b[0];
  }
  grid.sync();

  // ---- P1: dots. Each block owns 32 consecutive rows, 4 rows per sweep. ----
  for (int c = tid; c < 2304; c += 256) w3s[c] = ws[W3_OFF + c];
  __syncthreads();
  {
    const float4* w0p = (const float4*)(w3s);
    const float4* w1p = (const float4*)(w3s + DD);
    const float4* w2p = (const float4*)(w3s + 2 * DD);
    float* e0 = ws + E0_OFF;
    float* e1 = ws + E1_OFF;
    float* e2 = ws + E2_OFF;
    int base = blk * 32;
#pragma unroll 2
    for (int it = 0; it < 8; ++it) {
      int row = base + it * 4 + wave;
      const float4* xr = (const float4*)(x + (size_t)row * DD);
      float a0 = 0.f, a1 = 0.f, a2 = 0.f;
#pragma unroll
      for (int q = 0; q < 3; ++q) {
        int f = lane + q * 64; // float4 index, 192 per row
        float4 xv = xr[f];
        float4 w0 = w0p[f], w1 = w1p[f], w2 = w2p[f];
        a0 += w0.x * xv.x + w0.y * xv.y + w0.z * xv.z + w0.w * xv.w;
        a1 += w1.x * xv.x + w1.y * xv.y + w1.z * xv.z + w1.w * xv.w;
        a2 += w2.x * xv.x + w2.y * xv.y + w2.z * xv.z + w2.w * xv.w;
      }
#pragma unroll
      for (int m = 1; m < 64; m <<= 1) {
        a0 += __shfl_xor(a0, m);
        a1 += __shfl_xor(a1, m);
        a2 += __shfl_xor(a2, m);
      }
      if (lane == 0) { e0[row] = a0; e1[row] = a1; e2[row] = a2; }
    }
  }
  grid.sync();

  // ---- P2: per-batch scan on blocks [0,16). alpha fused here. ----
  if (blk < BB) {
    int b = blk;
    const float* e0 = ws + E0_OFF + b * SS;
    const float* e1 = ws + E1_OFF + b * SS;
    const float* e2 = ws + E2_OFF + b * SS;
    float* wcur = ws + WCUR_OFF;
    float* wnext = ws + WNEXT_OFF;
    int* ft = (int*)(ws + FT_OFF);
    int* lenws = (int*)(ws + LEN_OFF);
    float bias = ws[BIAS_OFF];
    int len = lens[b];
    int t0 = tid * 8;
    float a[8];
    double incl[8];
    double run = 0.0;
#pragma unroll
    for (int e = 0; e < 8; ++e) {
      int t = t0 + e;
      float z = bias + e1[t];
      if (t > 0) z += e0[t - 1];
      if (t < SS - 1) z += e2[t + 1];
      float av = 1.f / (1.f + expf(-z));
      a[e] = (t < len) ? av : 0.f;
      run += (double)a[e];
      incl[e] = run;
    }
    sscan[tid] = run;
    __syncthreads();
    for (int off = 1; off < 256; off <<= 1) {
      double v = (tid >= off) ? sscan[tid - off] : 0.0;
      __syncthreads();
      sscan[tid] += v;
      __syncthreads();
    }
    double excl = (tid == 0) ? 0.0 : sscan[tid - 1];
    double Pprev = excl;
    int Fprev = (int)floor(excl);
#pragma unroll
    for (int e = 0; e < 8; ++e) {
      int t = t0 + e;
      double P = excl + incl[e];
      int F = (int)floor(P);
      bool fire = (F > Fprev); // alpha in [0,1] => F steps by at most 1
      float wc = fire ? (float)((double)F - Pprev) : a[e];
      float wn = fire ? (float)(P - (double)F) : 0.f;
      wcur[b * SS + t] = wc;
      wnext[b * SS + t] = wn;
      if (fire) ft[b * SS + (F - 1)] = t;
      Pprev = P;
      Fprev = F;
    }
    if (tid == 0) {
      int L = (int)floor(sscan[255]);
      lenws[b] = L;
      out[(size_t)NROW * DD + b] = (float)L;
    }
  }
  grid.sync();

  // ---- P3: emit. Each block owns 32 consecutive output rows, 4 per sweep. ----
  {
    const float* wcur = ws + WCUR_OFF;
    const float* wnext = ws + WNEXT_OFF;
    const int* ft = (const int*)(ws + FT_OFF);
    const int* lenws = (const int*)(ws + LEN_OFF);
    int base = blk * 32;
    for (int it = 0; it < 8; ++it) {
      int row = base + it * 4 + wave; // b*SS + j
      int b = row >> 11, j = row & (SS - 1);
      float4* orow = (float4*)(out + (size_t)row * DD);
      int L = lenws[b];
      if (j >= L) {
        float4 z = {0.f, 0.f, 0.f, 0.f};
        orow[lane] = z;
        orow[lane + 64] = z;
        orow[lane + 128] = z;
        continue;
      }
      int start = (j == 0) ? 0 : ft[b * SS + j - 1];
      int end = ft[b * SS + j];
      float4 acc0 = {0, 0, 0, 0}, acc1 = {0, 0, 0, 0}, acc2 = {0, 0, 0, 0};
      for (int t = start; t <= end; ++t) {
        float w = (j > 0 && t == start) ? wnext[b * SS + t] : wcur[b * SS + t];
        const float4* xr = (const float4*)(x + ((size_t)b * SS + t) * DD);
        float4 v0 = xr[lane], v1 = xr[lane + 64], v2 = xr[lane + 128];
        acc0.x = fmaf(w, v0.x, acc0.x); acc0.y = fmaf(w, v0.y, acc0.y);
        acc0.z = fmaf(w, v0.z, acc0.z); acc0.w = fmaf(w, v0.w, acc0.w);
        acc1.x = fmaf(w, v1.x, acc1.x); acc1.y = fmaf(w, v1.y, acc1.y);
        acc1.z = fmaf(w, v1.z, acc1.z); acc1.w = fmaf(w, v1.w, acc1.w);
        acc2.x = fmaf(w, v2.x, acc2.x); acc2.y = fmaf(w, v2.y, acc2.y);
        acc2.z = fmaf(w, v2.z, acc2.z); acc2.w = fmaf(w, v2.w, acc2.w);
      }
      orow[lane] = acc0;
      orow[lane + 64] = acc1;
      orow[lane + 128] = acc2;
    }
  }
}

extern "C" void kernel_launch(void* const* d_in, const int* in_sizes, int n_in,
                              void* d_out, int out_size, void* d_ws, size_t ws_size,
                              hipStream_t stream) {
  const float* x      = (const float*)d_in[0]; // (B,S,D)
  const int*   lens   = (const int*)d_in[1];   // (B,)
  const float* conv_w = (const float*)d_in[2]; // (D,D,3)
  const float* conv_b = (const float*)d_in[3]; // (D,)
  const float* lin_w  = (const float*)d_in[4]; // (1,D)
  const float* lin_b  = (const float*)d_in[5]; // (1,)
  float* out = (float*)d_out;                  // B*S*D floats then B lens (as float)
  float* ws = (float*)d_ws;

  void* kargs[] = {
    (void*)&x, (void*)&lens, (void*)&conv_w, (void*)&conv_b,
    (void*)&lin_w, (void*)&lin_b, (void*)&ws, (void*)&out,
  };
  hipLaunchCooperativeKernel(reinterpret_cast<void*>(cif_mega),
                             dim3(NBLK), dim3(256), kargs, 0u, stream);
}

// Round 4
// 202.416 us; speedup vs baseline: 3.2724x; 3.2724x over previous
//
#include <hip/hip_runtime.h>
#include <math.h>

#define BB 16
#define SS 2048
#define DD 768
#define NROW (BB * SS) // 32768
#define NSLICE 16      // o-dimension split for weight fold

// ws layout (float offsets)
#define PART_OFF  0                        // NSLICE*2304 floats: partial w3 sums
#define W3_OFF    (PART_OFF + NSLICE*2304) // 2304 floats: w3[k][i]
#define BIAS_OFF  (W3_OFF + 2304)          // 1 float
#define E0_OFF    (BIAS_OFF + 64)          // NROW floats each
#define E1_OFF    (E0_OFF + NROW)
#define E2_OFF    (E1_OFF + NROW)
#define WCUR_OFF  (E2_OFF + NROW)          // NROW floats
#define WNEXT_OFF (WCUR_OFF + NROW)        // NROW floats
#define FT_OFF    (WNEXT_OFF + NROW)       // NROW ints: fire time of output row j
#define LEN_OFF   (FT_OFF + NROW)          // BB ints

// K1a: partial fold over an o-slice. grid = NSLICE*9 blocks.
__global__ __launch_bounds__(256) void k1a_fold_part(
    const float* __restrict__ conv_w, const float* __restrict__ lin_w,
    float* __restrict__ ws) {
  int tid = threadIdx.x;
  int slice = blockIdx.x / 9, cb = blockIdx.x % 9;
  int c = cb * 256 + tid; // c in [0,2304)
  int o0 = slice * (DD / NSLICE);
  float acc = 0.f;
#pragma unroll 4
  for (int oo = 0; oo < DD / NSLICE; ++oo) {
    int o = o0 + oo;
    acc = fmaf(lin_w[o], conv_w[(size_t)o * 2304 + c], acc); // coalesced over c
  }
  ws[PART_OFF + slice * 2304 + c] = acc;
}

// K1r: reduce partials -> w3[k*DD+i]; block 9 computes bias_eff.
__global__ __launch_bounds__(256) void k1r_fold_reduce(
    const float* __restrict__ conv_b, const float* __restrict__ lin_w,
    const float* __restrict__ lin_b, float* __restrict__ ws) {
  __shared__ float red[256];
  int tid = threadIdx.x;
  if (blockIdx.x < 9) {
    int c = blockIdx.x * 256 + tid;
    float acc = 0.f;
#pragma unroll
    for (int s = 0; s < NSLICE; ++s) acc += ws[PART_OFF + s * 2304 + c];
    int i = c / 3, k = c % 3;
    ws[W3_OFF + k * DD + i] = acc;
  } else {
    float p = 0.f;
    for (int o = tid; o < DD; o += 256) p = fmaf(lin_w[o], conv_b[o], p);
    red[tid] = p;
    __syncthreads();
    for (int off = 128; off > 0; off >>= 1) {
      if (tid < off) red[tid] += red[tid + off];
      __syncthreads();
    }
    if (tid == 0) ws[BIAS_OFF] = red[0] + lin_b[0];
  }
}

// K2a: per encoder row t, e_k[t] = sum_i w3[k][i]*x[t][i]. One wave per row,
// 4 rows per block. SKIPS rows with s > len[b] (alpha masked there anyway;
// stencil needs e up to index len).
__global__ __launch_bounds__(256) void k2a_dots(
    const float* __restrict__ x, const float* __restrict__ ws,
    const int* __restrict__ lens,
    float* __restrict__ e0, float* __restrict__ e1, float* __restrict__ e2) {
  __shared__ float w3[2304];
  int tid = threadIdx.x;
  int wave = tid >> 6, lane = tid & 63;
  int row = blockIdx.x * 4 + wave; // < NROW; all 4 rows share b (512 blocks/batch)
  int b = row >> 11, s = row & (SS - 1);
  bool active = (s <= lens[b]);
  for (int c = tid; c < 2304; c += 256) w3[c] = ws[W3_OFF + c];
  __syncthreads();
  if (!active) return;
  const float4* xr = (const float4*)(x + (size_t)row * DD);
  const float4* w0p = (const float4*)(w3);
  const float4* w1p = (const float4*)(w3 + DD);
  const float4* w2p = (const float4*)(w3 + 2 * DD);
  float a0 = 0.f, a1 = 0.f, a2 = 0.f;
#pragma unroll
  for (int q = 0; q < 3; ++q) {
    int f = lane + q * 64; // float4 index, 192 per row
    float4 xv = xr[f];
    float4 w0 = w0p[f], w1 = w1p[f], w2 = w2p[f];
    a0 += w0.x * xv.x + w0.y * xv.y + w0.z * xv.z + w0.w * xv.w;
    a1 += w1.x * xv.x + w1.y * xv.y + w1.z * xv.z + w1.w * xv.w;
    a2 += w2.x * xv.x + w2.y * xv.y + w2.z * xv.z + w2.w * xv.w;
  }
#pragma unroll
  for (int m = 1; m < 64; m <<= 1) {
    a0 += __shfl_xor(a0, m);
    a1 += __shfl_xor(a1, m);
    a2 += __shfl_xor(a2, m);
  }
  if (lane == 0) { e0[row] = a0; e1[row] = a1; e2[row] = a2; }
}

// K3: fused alpha (stencil+sigmoid+mask) + per-batch prefix scan (wave shuffles,
// single barrier). aacc_t = P_t - floor(P_t); fire where floor increments.
__global__ __launch_bounds__(256) void k3_scan(
    const float* __restrict__ ws_ro, const int* __restrict__ lens,
    float* __restrict__ wcur, float* __restrict__ wnext, int* __restrict__ ft,
    int* __restrict__ lenws, float* __restrict__ out_len) {
  __shared__ double wtot[4];
  int b = blockIdx.x, tid = threadIdx.x;
  int wave = tid >> 6, lane = tid & 63;
  const float* e0 = ws_ro + E0_OFF + b * SS;
  const float* e1 = ws_ro + E1_OFF + b * SS;
  const float* e2 = ws_ro + E2_OFF + b * SS;
  float bias = ws_ro[BIAS_OFF];
  int len = lens[b];
  int t0 = tid * 8;
  float a[8];
  double incl[8];
  double run = 0.0;
#pragma unroll
  for (int e = 0; e < 8; ++e) {
    int t = t0 + e;
    float av = 0.f;
    if (t < len) { // e-values valid only for s <= len
      float z = bias + e1[t];
      if (t > 0) z += e0[t - 1];
      z += e2[t + 1]; // t+1 <= len always computed
      av = 1.f / (1.f + expf(-z));
    }
    a[e] = av;
    run += (double)av;
    incl[e] = run;
  }
  // inclusive shuffle-scan of per-thread totals within each wave
  double v = run;
#pragma unroll
  for (int m = 1; m < 64; m <<= 1) {
    double o = __shfl_up(v, m);
    if (lane >= m) v += o;
  }
  if (lane == 63) wtot[wave] = v;
  __syncthreads();
  double woff = 0.0;
  for (int w = 0; w < wave; ++w) woff += wtot[w];
  double excl = woff + v - run; // exclusive prefix for this thread's 8 elements
  double Pprev = excl;
  int Fprev = (int)floor(excl);
#pragma unroll
  for (int e = 0; e < 8; ++e) {
    int t = t0 + e;
    double P = excl + incl[e];
    int F = (int)floor(P);
    bool fire = (F > Fprev); // alpha in [0,1) => F steps by at most 1
    float wc = fire ? (float)((double)F - Pprev) : a[e];
    float wn = fire ? (float)(P - (double)F) : 0.f;
    wcur[b * SS + t] = wc;
    wnext[b * SS + t] = wn;
    if (fire) ft[b * SS + (F - 1)] = t;
    Pprev = P;
    Fprev = F;
  }
  if (tid == 255) {
    int L = (int)floor(woff + v);
    lenws[b] = L;
    out_len[b] = (float)L;
  }
}

// K4: one wave per output row j. Row j = wnext[ft[j-1]]*x[ft[j-1]]
//   + sum_{ft[j-1] < t < ft[j]} wcur[t]*x[t] + wcur[ft[j]]*x[ft[j]]. j>=L -> zeros.
__global__ __launch_bounds__(256) void k4_emit(
    const float* __restrict__ x, const float* __restrict__ wcur,
    const float* __restrict__ wnext, const int* __restrict__ ft,
    const int* __restrict__ lenws, float* __restrict__ out) {
  int tid = threadIdx.x, wave = tid >> 6, lane = tid & 63;
  int row = blockIdx.x * 4 + wave; // b*SS + j
  int b = row >> 11, j = row & (SS - 1);
  float4* orow = (float4*)(out + (size_t)row * DD);
  int L = lenws[b];
  if (j >= L) {
    float4 z = {0.f, 0.f, 0.f, 0.f};
    orow[lane] = z;
    orow[lane + 64] = z;
    orow[lane + 128] = z;
    return;
  }
  int start = (j == 0) ? 0 : ft[b * SS + j - 1];
  int end = ft[b * SS + j];
  float4 acc0 = {0, 0, 0, 0}, acc1 = {0, 0, 0, 0}, acc2 = {0, 0, 0, 0};
  for (int t = start; t <= end; ++t) {
    float w = (j > 0 && t == start) ? wnext[b * SS + t] : wcur[b * SS + t];
    const float4* xr = (const float4*)(x + ((size_t)b * SS + t) * DD);
    float4 v0 = xr[lane], v1 = xr[lane + 64], v2 = xr[lane + 128];
    acc0.x = fmaf(w, v0.x, acc0.x); acc0.y = fmaf(w, v0.y, acc0.y);
    acc0.z = fmaf(w, v0.z, acc0.z); acc0.w = fmaf(w, v0.w, acc0.w);
    acc1.x = fmaf(w, v1.x, acc1.x); acc1.y = fmaf(w, v1.y, acc1.y);
    acc1.z = fmaf(w, v1.z, acc1.z); acc1.w = fmaf(w, v1.w, acc1.w);
    acc2.x = fmaf(w, v2.x, acc2.x); acc2.y = fmaf(w, v2.y, acc2.y);
    acc2.z = fmaf(w, v2.z, acc2.z); acc2.w = fmaf(w, v2.w, acc2.w);
  }
  orow[lane] = acc0;
  orow[lane + 64] = acc1;
  orow[lane + 128] = acc2;
}

extern "C" void kernel_launch(void* const* d_in, const int* in_sizes, int n_in,
                              void* d_out, int out_size, void* d_ws, size_t ws_size,
                              hipStream_t stream) {
  const float* x      = (const float*)d_in[0]; // (B,S,D)
  const int*   lens   = (const int*)d_in[1];   // (B,)
  const float* conv_w = (const float*)d_in[2]; // (D,D,3)
  const float* conv_b = (const float*)d_in[3]; // (D,)
  const float* lin_w  = (const float*)d_in[4]; // (1,D)
  const float* lin_b  = (const float*)d_in[5]; // (1,)
  float* out = (float*)d_out;                  // B*S*D floats then B lens (as float)
  float* ws = (float*)d_ws;

  float* e0 = ws + E0_OFF;
  float* e1 = ws + E1_OFF;
  float* e2 = ws + E2_OFF;
  float* wc = ws + WCUR_OFF;
  float* wn = ws + WNEXT_OFF;
  int* ft = (int*)(ws + FT_OFF);
  int* lenws = (int*)(ws + LEN_OFF);
  float* out_len = out + (size_t)NROW * DD;

  k1a_fold_part<<<NSLICE * 9, 256, 0, stream>>>(conv_w, lin_w, ws);
  k1r_fold_reduce<<<10, 256, 0, stream>>>(conv_b, lin_w, lin_b, ws);
  k2a_dots<<<NROW / 4, 256, 0, stream>>>(x, ws, lens, e0, e1, e2);
  k3_scan<<<BB, 256, 0, stream>>>(ws, lens, wc, wn, ft, lenws, out_len);
  k4_emit<<<NROW / 4, 256, 0, stream>>>(x, wc, wn, ft, lenws, out);
}